// Round 6
// baseline (610.959 us; speedup 1.0000x reference)
//
#include <hip/hip_runtime.h>
#include <stdint.h>

// GCN: out[u] = (sum_{(u,v) in E} x[v]) @ W + bias, E sorted by u.
// R5 was grid-limited: 782 blocks = 12 waves/CU (occupancy 24%), all pipes
// idle. R6: 8 rows/wave (grid 2x -> 24 waves/CU), wave-pairs share one
// 16-row MFMA tile (one barrier, waves split output cols); setup row_ptr by
// O(E) scatter at eu transitions (no serial binary searches); dead predicated
// gathers retarget row 0 (L2-hot); nontemporal out-stores keep L2 for x.

typedef __attribute__((ext_vector_type(8))) short bf16x8;   // 8 bf16 = 4 VGPRs
typedef __attribute__((ext_vector_type(4))) float f32x4;    // MFMA C/D

#define WSTRIDE 136   // A-tile k-stride (bf16 elems), multiple of 8 for 16B reads

__device__ __forceinline__ unsigned short f2bf(float f) {
    union { float f; uint32_t u; } c; c.f = f;
    uint32_t u = c.u;
    uint32_t r = (u + 0x7FFFu + ((u >> 16) & 1u)) >> 16;  // RNE
    return (unsigned short)r;
}

__global__ __launch_bounds__(256)
void gcn_setup(const int* __restrict__ eu, const float* __restrict__ W,
               int* __restrict__ row_ptr, unsigned short* __restrict__ Wg,
               int N, int E)
{
    const int g = blockIdx.x * 256 + threadIdx.x;
    // row_ptr[r] = lower_bound(eu, r), via transition scatter (eu sorted).
    if (g <= E) {
        int cur  = (g < E) ? eu[g] : N;        // virtual eu[E] = N
        int prev = (g > 0) ? eu[g - 1] : -1;   // virtual eu[-1] = -1
        for (int r = prev + 1; r <= cur; ++r) row_ptr[r] = g;
    }
    const int w = g - (E + 1);                 // W^T bf16: Wg[n*128+k] = bf16(W[k][n])
    if (w >= 0 && w < 16384) {
        int n = w >> 7, k = w & 127;
        Wg[w] = f2bf(W[k * 128 + n]);
    }
}

__global__ __launch_bounds__(256)
void gcn_main(const float* __restrict__ x,
              const int* __restrict__ ev,        // src ids, int32
              const int* __restrict__ row_ptr,   // [N+1]
              const unsigned short* __restrict__ Wg,  // bf16 W^T [128][128]
              const float* __restrict__ bias,
              float* __restrict__ out,           // [N][128] f32
              int N, int E)
{
    __shared__ __align__(16) unsigned short At[2][16 * WSTRIDE]; // per wave-pair

    const int t    = threadIdx.x;
    const int wid  = t >> 6;
    const int lane = t & 63;
    const int quad = lane >> 4;
    const int l15  = lane & 15;
    const int half = lane >> 5;   // 0/1: which edge of the pair
    const int l31  = lane & 31;   // float4 slot within a 128-f row

    const int blockrow = blockIdx.x * 32;
    const int rowbase  = blockrow + wid * 8;   // this wave's 8 rows

    // ---- Row boundaries: one coalesced load (CSR precomputed) ----
    const int bq  = rowbase + (lane < 9 ? lane : 8);
    const int bnd = row_ptr[min(bq, N)];

    // wave wid writes rows (wid&1)*8 + m of tile (wid>>1)
    unsigned short* Am = &At[wid >> 1][(wid & 1) * 8 * WSTRIDE];
    const float4* x4 = (const float4*)x;

    // prefetch row 0's first 64 edge indices
    int vIdx = ev[min(__shfl(bnd, 0) + lane, E - 1)];

    for (int m = 0; m < 8; ++m) {
        const int s  = __shfl(bnd, m);
        const int sn = __shfl(bnd, m + 1);
        const int c  = sn - s;
        // prefetch next row's indices BEFORE this row's gather-wait
        int vNext = (m < 7) ? ev[min(sn + lane, E - 1)] : 0;

        float4 acc0 = {0.f, 0.f, 0.f, 0.f};
        float4 acc1 = {0.f, 0.f, 0.f, 0.f};
        for (int base = 0; base < c; base += 16) {
            if (base && ((base & 63) == 0))               // c > 64: rare
                vIdx = ev[min(s + base + lane, E - 1)];
            const int boff = base & 63;
            float4 tv[8];
            float  sc[8];
            #pragma unroll
            for (int k = 0; k < 8; ++k) {                 // issue ALL loads first
                const int eidx = base + 2 * k + half;
                const int slot = (boff + 2 * k + half) & 63;
                int v = __shfl(vIdx, slot);
                const bool act = (eidx < c);
                sc[k] = act ? 1.0f : 0.0f;
                v = act ? v : 0;                          // dead loads hit row 0 (hot)
                tv[k] = x4[((long long)v << 5) + l31];
            }
            #pragma unroll
            for (int k = 0; k < 8; ++k) {                 // one wait, then fma
                float4& a = (k & 1) ? acc1 : acc0;
                a.x = fmaf(tv[k].x, sc[k], a.x);
                a.y = fmaf(tv[k].y, sc[k], a.y);
                a.z = fmaf(tv[k].z, sc[k], a.z);
                a.w = fmaf(tv[k].w, sc[k], a.w);
            }
        }
        vIdx = vNext;

        // combine accumulator pair, then the two wave halves
        acc0.x += acc1.x; acc0.y += acc1.y; acc0.z += acc1.z; acc0.w += acc1.w;
        acc0.x += __shfl_xor(acc0.x, 32);
        acc0.y += __shfl_xor(acc0.y, 32);
        acc0.z += __shfl_xor(acc0.z, 32);
        acc0.w += __shfl_xor(acc0.w, 32);
        if (half == 0) {   // lane l31 owns features 4*l31 .. 4*l31+3
            ushort4 pk;
            pk.x = f2bf(acc0.x); pk.y = f2bf(acc0.y);
            pk.z = f2bf(acc0.z); pk.w = f2bf(acc0.w);
            *(ushort4*)(Am + m * WSTRIDE + 4 * l31) = pk;   // 8B aligned
        }
    }
    __syncthreads();   // wave-pair shares its 16-row tile

    // ---- MFMA: pair p's 16 rows x 64 cols per wave (ch = col half) ----
    const int p  = wid >> 1;
    const int ch = wid & 1;
    const unsigned short* Ar = &At[p][0];
    f32x4 acc[4];
    #pragma unroll
    for (int nt = 0; nt < 4; ++nt) { acc[nt].x = 0.f; acc[nt].y = 0.f; acc[nt].z = 0.f; acc[nt].w = 0.f; }

    #pragma unroll
    for (int ks = 0; ks < 4; ++ks) {
        const int kofs = ks * 32 + quad * 8;
        bf16x8 a = *(const bf16x8*)(Ar + l15 * WSTRIDE + kofs);       // A[m=l15][k..]
        #pragma unroll
        for (int nt = 0; nt < 4; ++nt) {
            const int col = ch * 64 + nt * 16 + l15;
            bf16x8 b = *(const bf16x8*)(Wg + col * 128 + kofs);       // B^T[n=col][k..]
            acc[nt] = __builtin_amdgcn_mfma_f32_16x16x32_bf16(a, b, acc[nt], 0, 0, 0);
        }
    }

    // ---- Epilogue. C/D: col = lane&15, row = quad*4 + reg ----
    #pragma unroll
    for (int nt = 0; nt < 4; ++nt) {
        const int col = ch * 64 + nt * 16 + l15;
        const float bcol = bias[col];
        #pragma unroll
        for (int r = 0; r < 4; ++r) {
            const int row = blockrow + p * 16 + quad * 4 + r;
            if (row < N)
                __builtin_nontemporal_store(acc[nt][r] + bcol,
                                            &out[(long long)row * 128 + col]);
        }
    }
}

extern "C" void kernel_launch(void* const* d_in, const int* in_sizes, int n_in,
                              void* d_out, int out_size, void* d_ws, size_t ws_size,
                              hipStream_t stream) {
    const float* x    = (const float*)d_in[0];
    const int*   ei   = (const int*)d_in[1];     // int32 on device
    const float* W    = (const float*)d_in[2];
    const float* bias = (const float*)d_in[3];
    float*       out  = (float*)d_out;

    const int N = in_sizes[0] / 128;
    const int E = in_sizes[1] / 2;

    int*            row_ptr = (int*)d_ws;                                  // (N+1)*4 B
    unsigned short* Wg      = (unsigned short*)((char*)d_ws + (((size_t)(N + 1) * 4 + 255) & ~(size_t)255)); // 32 KB

    const int setup_threads = (E + 1) + 16384;
    gcn_setup<<<(setup_threads + 255) / 256, 256, 0, stream>>>(ei, W, row_ptr, Wg, N, E);

    const int grid = (N + 31) / 32;   // 32 rows/block, 8 per wave
    gcn_main<<<grid, 256, 0, stream>>>(x, ei + E, row_ptr, Wg, bias, out, N, E);
}

// Round 7
// 134.155 us; speedup vs baseline: 4.5541x; 4.5541x over previous
//
#include <hip/hip_runtime.h>
#include <stdint.h>

// GCN: out[u] = (sum_{(u,v) in E} x[v]) @ W + bias, E sorted by u.
// R6 post-mortem: lin=unique[:E] keeps the SMALLEST E values -> only rows
// 0..~N/2 have edges (avg deg ~25.6 there). Two consequences fixed here:
//  (a) setup's transition scatter had ONE thread serially filling ~25k tail
//      rows (526us!). Now: bounded interior scatter + parallel tail fill.
//  (b) row-contiguous wave assignment was 2x load-imbalanced. Now waves own
//      rows {wg + m*TW} (TW = total waves): every wave ~4 populated rows,
//      perfect static balance. Tile position is logical; epilogue stores are
//      64B-segment scatters either way, so remapping is free.

typedef __attribute__((ext_vector_type(8))) short bf16x8;   // 8 bf16 = 4 VGPRs
typedef __attribute__((ext_vector_type(4))) float f32x4;    // MFMA C/D

#define WSTRIDE 136   // A-tile k-stride (bf16 elems), multiple of 8 for 16B reads

__device__ __forceinline__ unsigned short f2bf(float f) {
    union { float f; uint32_t u; } c; c.f = f;
    uint32_t u = c.u;
    uint32_t r = (u + 0x7FFFu + ((u >> 16) & 1u)) >> 16;  // RNE
    return (unsigned short)r;
}

__global__ __launch_bounds__(256)
void gcn_setup(const int* __restrict__ eu, const float* __restrict__ W,
               int* __restrict__ row_ptr, unsigned short* __restrict__ Wg,
               int N, int E)
{
    const int g = blockIdx.x * 256 + threadIdx.x;
    // Interior transitions: thread g writes rows (eu[g-1], eu[g]] = g.
    // Interior gaps are tiny (Poisson-dense rows); tail handled below.
    if (g < E) {
        int cur  = eu[g];
        int prev = (g > 0) ? eu[g - 1] : -1;
        for (int r = prev + 1; r <= cur; ++r) row_ptr[r] = g;
    }
    // Parallel tail fill: rows past the last populated row get E.
    if (g <= N) {
        int last = eu[E - 1];          // same address all threads: L2 broadcast
        if (g > last) row_ptr[g] = E;
    }
    // W^T bf16: coalesced read, scattered 2B write (one-time, tiny)
    if (g < 16384) {
        int k = g >> 7, n = g & 127;
        Wg[n * 128 + k] = f2bf(W[g]);
    }
}

__global__ __launch_bounds__(256)
void gcn_main(const float* __restrict__ x,
              const int* __restrict__ ev,        // src ids, int32
              const int* __restrict__ row_ptr,   // [N+1]
              const unsigned short* __restrict__ Wg,  // bf16 W^T [128][128]
              const float* __restrict__ bias,
              float* __restrict__ out,           // [N][128] f32
              int N, int E, int TW)              // TW = grid*4 (total waves)
{
    __shared__ __align__(16) unsigned short At[2][16 * WSTRIDE]; // per wave-pair

    const int t    = threadIdx.x;
    const int wid  = t >> 6;
    const int lane = t & 63;
    const int quad = lane >> 4;
    const int l15  = lane & 15;
    const int half = lane >> 5;   // 0/1: which edge of a pair
    const int l31  = lane & 31;   // float4 slot within a 128-f row

    const int wg = blockIdx.x * 4 + wid;   // global wave id; rows = wg + m*TW

    // ---- Row boundaries: lanes 0-7 -> starts, lanes 8-15 -> ends ----
    int bnd;
    {
        const int m8 = lane & 7;
        const int e8 = (lane >> 3) & 1;
        const int ridx = min(wg + m8 * TW + e8, N);
        bnd = row_ptr[ridx];
    }

    unsigned short* Am = &At[wid >> 1][(wid & 1) * 8 * WSTRIDE];
    const float4* x4 = (const float4*)x;

    // prefetch row 0's first 64 edge indices
    int vIdx = ev[min(__shfl(bnd, 0) + lane, E - 1)];

    for (int m = 0; m < 8; ++m) {
        const int s = __shfl(bnd, m);
        const int c = __shfl(bnd, m + 8) - s;
        // prefetch next row's indices BEFORE this row's gather-wait
        int vNext = (m < 7) ? ev[min(__shfl(bnd, m + 1) + lane, E - 1)] : 0;

        float4 acc0 = {0.f, 0.f, 0.f, 0.f};
        float4 acc1 = {0.f, 0.f, 0.f, 0.f};
        for (int base = 0; base < c; base += 16) {
            if (base && ((base & 63) == 0))               // c > 64: never here
                vIdx = ev[min(s + base + lane, E - 1)];
            const int boff = base & 63;
            float4 tv[8];
            float  sc[8];
            #pragma unroll
            for (int k = 0; k < 8; ++k) {                 // issue ALL loads first
                const int eidx = base + 2 * k + half;
                const int slot = (boff + 2 * k + half) & 63;
                int v = __shfl(vIdx, slot);
                const bool act = (eidx < c);
                sc[k] = act ? 1.0f : 0.0f;
                v = act ? v : 0;                          // dead loads hit hot row 0
                tv[k] = x4[((long long)v << 5) + l31];
            }
            #pragma unroll
            for (int k = 0; k < 8; ++k) {                 // one wait, then fma
                float4& a = (k & 1) ? acc1 : acc0;
                a.x = fmaf(tv[k].x, sc[k], a.x);
                a.y = fmaf(tv[k].y, sc[k], a.y);
                a.z = fmaf(tv[k].z, sc[k], a.z);
                a.w = fmaf(tv[k].w, sc[k], a.w);
            }
        }
        vIdx = vNext;

        // combine accumulator pair, then the two wave halves
        acc0.x += acc1.x; acc0.y += acc1.y; acc0.z += acc1.z; acc0.w += acc1.w;
        acc0.x += __shfl_xor(acc0.x, 32);
        acc0.y += __shfl_xor(acc0.y, 32);
        acc0.z += __shfl_xor(acc0.z, 32);
        acc0.w += __shfl_xor(acc0.w, 32);
        if (half == 0) {   // lane l31 owns features 4*l31 .. 4*l31+3
            ushort4 pk;
            pk.x = f2bf(acc0.x); pk.y = f2bf(acc0.y);
            pk.z = f2bf(acc0.z); pk.w = f2bf(acc0.w);
            *(ushort4*)(Am + m * WSTRIDE + 4 * l31) = pk;   // 8B aligned
        }
    }
    __syncthreads();   // wave-pair shares its 16-row tile

    // ---- MFMA: pair p's 16 logical rows x 64 cols per wave ----
    const int p  = wid >> 1;
    const int ch = wid & 1;
    const unsigned short* Ar = &At[p][0];
    f32x4 acc[4];
    #pragma unroll
    for (int nt = 0; nt < 4; ++nt) { acc[nt].x = 0.f; acc[nt].y = 0.f; acc[nt].z = 0.f; acc[nt].w = 0.f; }

    #pragma unroll
    for (int ks = 0; ks < 4; ++ks) {
        const int kofs = ks * 32 + quad * 8;
        bf16x8 a = *(const bf16x8*)(Ar + l15 * WSTRIDE + kofs);       // A[mi=l15][k..]
        #pragma unroll
        for (int nt = 0; nt < 4; ++nt) {
            const int col = ch * 64 + nt * 16 + l15;
            bf16x8 b = *(const bf16x8*)(Wg + col * 128 + kofs);       // B^T[n=col][k..]
            acc[nt] = __builtin_amdgcn_mfma_f32_16x16x32_bf16(a, b, acc[nt], 0, 0, 0);
        }
    }

    // ---- Epilogue. C/D: col = lane&15, mi = quad*4 + reg.
    // tile row mi -> physical row: half h = mi>>3, mm = mi&7,
    // row = (block*4 + 2p + h) + mm*TW ----
    const int wgpair = blockIdx.x * 4 + 2 * p;
    #pragma unroll
    for (int nt = 0; nt < 4; ++nt) {
        const int col = ch * 64 + nt * 16 + l15;
        const float bcol = bias[col];
        #pragma unroll
        for (int r = 0; r < 4; ++r) {
            const int mi  = quad * 4 + r;
            const int row = wgpair + (mi >> 3) + (mi & 7) * TW;
            if (row < N)
                __builtin_nontemporal_store(acc[nt][r] + bcol,
                                            &out[(long long)row * 128 + col]);
        }
    }
}

extern "C" void kernel_launch(void* const* d_in, const int* in_sizes, int n_in,
                              void* d_out, int out_size, void* d_ws, size_t ws_size,
                              hipStream_t stream) {
    const float* x    = (const float*)d_in[0];
    const int*   ei   = (const int*)d_in[1];     // int32 on device
    const float* W    = (const float*)d_in[2];
    const float* bias = (const float*)d_in[3];
    float*       out  = (float*)d_out;

    const int N = in_sizes[0] / 128;
    const int E = in_sizes[1] / 2;

    int*            row_ptr = (int*)d_ws;                                  // (N+1)*4 B
    unsigned short* Wg      = (unsigned short*)((char*)d_ws + (((size_t)(N + 1) * 4 + 255) & ~(size_t)255)); // 32 KB

    const int setup_threads = (E > N + 1 ? E : N + 1);
    gcn_setup<<<(setup_threads + 255) / 256, 256, 0, stream>>>(ei, W, row_ptr, Wg, N, E);

    const int grid = (N + 31) / 32;   // 32 logical rows/block, 8 per wave
    const int TW   = grid * 4;
    gcn_main<<<grid, 256, 0, stream>>>(x, ei + E, row_ptr, Wg, bias, out, N, E, TW);
}